// Round 11
// baseline (1236.961 us; speedup 1.0000x reference)
//
#include <hip/hip_runtime.h>

#define NPTS 65536          // B*N = 32*2048
#define HH 256
#define DIN 131
#define LAT 128
#define STEPS 5
#define DT 0.2f

typedef unsigned int uint;
typedef unsigned short ushort;
typedef __attribute__((ext_vector_type(8))) short short8;
typedef __attribute__((ext_vector_type(4))) float floatx4;
typedef __attribute__((ext_vector_type(4))) uint uintx4;

// Static LDS (27136 B): W1tab @0 (23040B): [s][kt][qq] 8 unit-records {wa,wc,ra,ba_s}
// (16B each, group stride 144B); W3tab @23040 (4096B): float4[j]={W3[0][j],W3[1][j],b2[j],0}
#define OFF_W3 23040
#define LDS_TOTAL 27136

__device__ __forceinline__ float tanh_fast(float x) {
    // tanh(x) = 1 - 2/(exp2(2x*log2e)+1); exact at both saturated ends.
    float e = __builtin_amdgcn_exp2f(x * 2.8853900817779268f);
    return 1.0f - 2.0f * __builtin_amdgcn_rcpf(e + 1.0f);
}

__device__ __forceinline__ ushort f2bf(float f) {
    uint u = __builtin_bit_cast(uint, f);
    u += 0x7fffu + ((u >> 16) & 1u);   // RNE
    return (ushort)(u >> 16);
}

// pack two f32 -> 2x bf16 (RNE) in one instruction; lo -> bits[15:0]
__device__ __forceinline__ uint cvt_pk_bf16(float lo, float hi) {
    uint r;
    asm("v_cvt_pk_bf16_f32 %0, %1, %2" : "=v"(r) : "v"(lo), "v"(hi));
    return r;
}

// ---- prep:
//  a1[b][h] = b1[h] + sum_l z[b][l]*W1[h][3+l]   (t=0 bias)
//  rs[h]    = sum_l W1[h][3+l]
//  wsw: W2 bf16 A-fragments:  wsw[((nt*8+kt)*64+lane)*8+j] = W2[n][k+j]
//  wss: MERGED tangent matrix W2s[n][k] = W2[n][k]*(W3[0][n]*W1[k][0] + W3[1][n]*W1[k][1])
//       in the same fragment layout.  (div = sum_j g2_j * (g1 . W2s^T)_j -- the two
//       tangent GEMMs collapse into one; W3/W1 column factors folded at prep time.)
//  n = nt*16+(lane&15), k = kt*32+(lane>>4)*8
__global__ void prep_kernel(const float* __restrict__ z, const float* __restrict__ W1,
                            const float* __restrict__ b1, const float* __restrict__ W2,
                            const float* __restrict__ W3,
                            float* __restrict__ a1, float* __restrict__ rsv,
                            ushort* __restrict__ wsw, ushort* __restrict__ wss)
{
    int tid = blockIdx.x * 256 + threadIdx.x;
    if (tid < 8192) {
        int b = tid >> 8, h = tid & 255;
        const float* wrow = W1 + h * DIN;
        const float* zb = z + b * LAT;
        float s = b1[h], r = 0.f;
        for (int l = 0; l < LAT; ++l) { float wv = wrow[3 + l]; s += wv * zb[l]; r += wv; }
        a1[tid] = s;
        if (b == 0) rsv[h] = r;
    } else {
        int t = tid - 8192;                    // 0..16383
        int which = t >> 13;                   // 0: wsw (W2), 1: wss (W2s)
        int tt = t & 8191;
        int lane = tt & 63, kt = (tt >> 6) & 7, nt = tt >> 9;
        int n = nt * 16 + (lane & 15);
        int k = kt * 32 + (lane >> 4) * 8;
        const float* src = W2 + n * HH + k;
        if (which == 0) {
            ushort* dst = wsw + tt * 8;
            #pragma unroll
            for (int j = 0; j < 8; ++j) dst[j] = f2bf(src[j]);
        } else {
            float w30n = W3[n], w31n = W3[HH + n];
            ushort* dst = wss + tt * 8;
            #pragma unroll
            for (int j = 0; j < 8; ++j) {
                int kk = k + j;
                float fold = w30n * W1[kk * DIN + 0] + w31n * W1[kk * DIN + 1];
                dst[j] = f2bf(src[j] * fold);
            }
        }
    }
}

// r11 = r10 barrier-free wave-complete structure + 2-GEMM merge + W2 from L2:
//  - frags 96->64 (h1,g1 only), acc 24->16, MFMA 384->256/wave-step, VALU -20%
//  - W2/W2s read straight from global (L2-resident 256KB/XCD; same addrs all waves)
//  - LDS = 27KB tables only -> occupancy register-limited: launch_bounds(256,3)
//    caps arch at ~84 (need ~55; frags+acc=80 go to AGPR <= ~86) -> 12 waves/CU,
//    3 waves/SIMD (r4-r10 invariant: every structure at 2 waves/SIMD = 180us;
//    latency-bound, bottom-up pipe demand ~50us).  Spill tripwire: FETCH/WRITE.
__global__ __launch_bounds__(256, 3) void cnf_kernel(
        const float* __restrict__ xin, const float* __restrict__ W1,
        const float* __restrict__ b2, const float* __restrict__ W3,
        const float* __restrict__ b3, const float* __restrict__ osc,
        const float* __restrict__ a1, const float* __restrict__ rsv,
        const ushort* __restrict__ wsw, const ushort* __restrict__ wss,
        float* __restrict__ out)
{
    __shared__ __align__(16) char sm[LDS_TOTAL];

    const int tid = threadIdx.x;
    const int lane = tid & 63;
    const int w = tid >> 6;                      // 4 independent waves
    const int r15 = lane & 15;
    const int q = lane >> 4;
    const int blk = blockIdx.x;
    const int b = blk >> 5;                      // 32 blocks per batch (64 pts/block)

    // ---- stage per-step layer-1 records + W3 projection table (all 256 threads) ----
    {
        const int h = tid;
        const int kt = h >> 5, rem = h & 31, qq = rem >> 3, u = rem & 7;
        const float wa = W1[h * DIN + 0];
        const float wc = W1[h * DIN + 1];
        const float wt = W1[h * DIN + 2];
        const float ra = rsv[h];
        const float ba = a1[b * HH + h];
        #pragma unroll
        for (int s = 0; s < STEPS; ++s) {
            float* rec = (float*)(sm + s * 4608 + kt * 576 + qq * 144 + u * 16);
            rec[0] = wa; rec[1] = wc; rec[2] = ra; rec[3] = ba + wt * ((float)s * DT);
        }
        float* w3r = (float*)(sm + OFF_W3 + h * 16);
        w3r[0] = W3[h]; w3r[1] = W3[HH + h]; w3r[2] = b2[h]; w3r[3] = 0.f;
    }

    // ---- per-lane state: point (lane&15), replicated across the 4 quads ----
    const int gp = blk * 64 + w * 16 + r15;
    float x0 = xin[gp * 2 + 0];
    float x1 = xin[gp * 2 + 1];
    float cc = 0.f;
    const float osdt = osc[0] * DT;
    const float b30 = b3[0], b31 = b3[1];

    __syncthreads();                             // the ONLY barrier

    const char* wtab = sm + q * 144;             // this quad's unit records
    const ushort* pw = wsw + (size_t)lane * 8;   // W2 frag base (global/L2)
    const ushort* ps = wss + (size_t)lane * 8;   // W2s frag base (global/L2)

    for (int s = 0; s < STEPS; ++s) {
        // ---- B-frag build: h1 and g1 only (scale folds live in W2s), 8 kt ----
        short8 B0[8], B1[8];
        const char* stab = wtab + s * 4608;
        #pragma unroll
        for (int kt = 0; kt < 8; ++kt) {
            const char* kr = stab + kt * 576;
            uint p0[4], p1[4];
            #pragma unroll
            for (int up = 0; up < 4; ++up) {
                const float4 cA = *(const float4*)(kr + up * 32);
                const float4 cB = *(const float4*)(kr + up * 32 + 16);
                float pa = cA.w + cA.x * x0 + cA.y * x1 + cA.z * cc;
                float pb = cB.w + cB.x * x0 + cB.y * x1 + cB.z * cc;
                float ha = tanh_fast(pa), hb = tanh_fast(pb);
                p0[up] = cvt_pk_bf16(ha, hb);
                p1[up] = cvt_pk_bf16(1.f - ha * ha, 1.f - hb * hb);
            }
            B0[kt] = __builtin_bit_cast(short8, (uintx4){p0[0], p0[1], p0[2], p0[3]});
            B1[kt] = __builtin_bit_cast(short8, (uintx4){p1[0], p1[1], p1[2], p1[3]});
        }

        // ---- 2 GEMMs (R0 = h1.W2^T, R12 = g1.W2s^T), 8 nt-passes, acc = 16 regs ----
        float sv0 = 0.f, sv1 = 0.f, sdv = 0.f;   // per-lane (= per-point) partials
        #pragma unroll
        for (int pass = 0; pass < 8; ++pass) {
            floatx4 a0[2], a12[2];
            #pragma unroll
            for (int n2 = 0; n2 < 2; ++n2) {
                a0[n2]  = (floatx4){0.f, 0.f, 0.f, 0.f};
                a12[n2] = (floatx4){0.f, 0.f, 0.f, 0.f};
            }
            #pragma unroll
            for (int kt = 0; kt < 8; ++kt) {
                #pragma unroll
                for (int n2 = 0; n2 < 2; ++n2) {
                    const int fo = ((pass * 2 + n2) * 8 + kt) * 512;
                    short8 wf0 = *(const short8*)(pw + fo);
                    short8 wfs = *(const short8*)(ps + fo);
                    a0[n2]  = __builtin_amdgcn_mfma_f32_16x16x32_bf16(wf0, B0[kt], a0[n2],  0, 0, 0);
                    a12[n2] = __builtin_amdgcn_mfma_f32_16x16x32_bf16(wfs, B1[kt], a12[n2], 0, 0, 0);
                }
            }
            // epilogue: lane's acc reg r is j = nt*16 + q*4 + r of its own point
            #pragma unroll
            for (int n2 = 0; n2 < 2; ++n2) {
                const float4* w3p = (const float4*)(sm + OFF_W3
                                   + (size_t)(((pass * 2 + n2) * 16 + q * 4) * 16));
                #pragma unroll
                for (int r = 0; r < 4; ++r) {
                    const float4 w3c = w3p[r];           // broadcast within quad
                    float h2 = tanh_fast(a0[n2][r] + w3c.z);
                    float g2 = 1.f - h2 * h2;
                    sv0 += h2 * w3c.x;
                    sv1 += h2 * w3c.y;
                    sdv += g2 * a12[n2][r];              // w30/w31 already folded in W2s
                }
            }
        }

        // ---- cross-quad reduction (4 j-subsets) + state update, all in-wave ----
        sv0 += __shfl_xor(sv0, 16);  sv0 += __shfl_xor(sv0, 32);
        sv1 += __shfl_xor(sv1, 16);  sv1 += __shfl_xor(sv1, 32);
        sdv += __shfl_xor(sdv, 16);  sdv += __shfl_xor(sdv, 32);
        x0 += (sv0 + b30) * osdt;
        x1 += (sv1 + b31) * osdt;
        cc += sdv * osdt;
    }

    if (q == 0) {                                // one quad stores (state replicated)
        out[gp * 2 + 0] = x0;
        out[gp * 2 + 1] = x1;
        out[NPTS * 2 + gp] = cc;                 // log_det
    }
}

extern "C" void kernel_launch(void* const* d_in, const int* in_sizes, int n_in,
                              void* d_out, int out_size, void* d_ws, size_t ws_size,
                              hipStream_t stream) {
    const float* x   = (const float*)d_in[0];
    const float* z   = (const float*)d_in[1];
    const float* W1  = (const float*)d_in[2];
    const float* b1  = (const float*)d_in[3];
    const float* W2  = (const float*)d_in[4];
    const float* b2  = (const float*)d_in[5];
    const float* W3  = (const float*)d_in[6];
    const float* b3  = (const float*)d_in[7];
    const float* osc = (const float*)d_in[8];

    // ws layout: a1 [8192 f] @0 | rs [256 f] @32768 | wsw [65536 bf16] @33792
    //            | wss [65536 bf16] @164864   (~290KB total)
    float* a1  = (float*)d_ws;
    float* rsv = (float*)((char*)d_ws + 32768);
    ushort* wsw = (ushort*)((char*)d_ws + 33792);
    ushort* wss = (ushort*)((char*)d_ws + 164864);

    hipLaunchKernelGGL(prep_kernel, dim3(96), dim3(256), 0, stream,
                       z, W1, b1, W2, W3, a1, rsv, wsw, wss);
    hipLaunchKernelGGL(cnf_kernel, dim3(1024), dim3(256), 0, stream,
                       x, W1, b2, W3, b3, osc, a1, rsv, wsw, wss, (float*)d_out);
}

// Round 12
// 487.537 us; speedup vs baseline: 2.5372x; 2.5372x over previous
//
#include <hip/hip_runtime.h>

#define NPTS 65536          // B*N = 32*2048
#define HH 256
#define DIN 131
#define LAT 128
#define STEPS 5
#define DT 0.2f

typedef unsigned int uint;
typedef unsigned short ushort;
typedef __attribute__((ext_vector_type(8))) short short8;
typedef __attribute__((ext_vector_type(4))) float floatx4;
typedef __attribute__((ext_vector_type(4))) uint uintx4;

// Dynamic LDS layout (158208 B, identical footprint to r10):
//   smWsw   @ 0      : 131072 B  W2 bf16 A-fragments (LDS pipe)
//   smW1tab @ 131072 :  23040 B  [s][kt][qq] 8 unit-records {wa,wc,ra,ba_s} (16B, stride 144B)
//   smW3    @ 154112 :   4096 B  float4[j] = {W3[0][j], W3[1][j], b2[j], 0}
#define OFF_W1TAB 131072
#define OFF_W3    154112
#define LDS_TOTAL 158208

__device__ __forceinline__ float tanh_fast(float x) {
    // tanh(x) = 1 - 2/(exp2(2x*log2e)+1); exact at both saturated ends.
    float e = __builtin_amdgcn_exp2f(x * 2.8853900817779268f);
    return 1.0f - 2.0f * __builtin_amdgcn_rcpf(e + 1.0f);
}

__device__ __forceinline__ ushort f2bf(float f) {
    uint u = __builtin_bit_cast(uint, f);
    u += 0x7fffu + ((u >> 16) & 1u);   // RNE
    return (ushort)(u >> 16);
}

// pack two f32 -> 2x bf16 (RNE) in one instruction; lo -> bits[15:0]
__device__ __forceinline__ uint cvt_pk_bf16(float lo, float hi) {
    uint r;
    asm("v_cvt_pk_bf16_f32 %0, %1, %2" : "=v"(r) : "v"(lo), "v"(hi));
    return r;
}

// ---- prep:
//  a1[b][h] = b1[h] + sum_l z[b][l]*W1[h][3+l]   (t=0 bias)
//  rs[h]    = sum_l W1[h][3+l]
//  wsw: W2 bf16 fragments:  wsw[((nt*8+kt)*64+lane)*8+j] = W2[n][k+j]
//  wss: MERGED tangent matrix W2s[n][k] = W2[n][k]*(W3[0][n]*W1[k][0]+W3[1][n]*W1[k][1])
//       (r11-verified algebra: div = sum_j g2_j * (g1 . W2s^T)_j), same frag layout.
//  n = nt*16+(lane&15), k = kt*32+(lane>>4)*8
__global__ void prep_kernel(const float* __restrict__ z, const float* __restrict__ W1,
                            const float* __restrict__ b1, const float* __restrict__ W2,
                            const float* __restrict__ W3,
                            float* __restrict__ a1, float* __restrict__ rsv,
                            ushort* __restrict__ wsw, ushort* __restrict__ wss)
{
    int tid = blockIdx.x * 256 + threadIdx.x;
    if (tid < 8192) {
        int b = tid >> 8, h = tid & 255;
        const float* wrow = W1 + h * DIN;
        const float* zb = z + b * LAT;
        float s = b1[h], r = 0.f;
        for (int l = 0; l < LAT; ++l) { float wv = wrow[3 + l]; s += wv * zb[l]; r += wv; }
        a1[tid] = s;
        if (b == 0) rsv[h] = r;
    } else {
        int t = tid - 8192;                    // 0..16383
        int which = t >> 13;                   // 0: wsw (W2), 1: wss (W2s)
        int tt = t & 8191;
        int lane = tt & 63, kt = (tt >> 6) & 7, nt = tt >> 9;
        int n = nt * 16 + (lane & 15);
        int k = kt * 32 + (lane >> 4) * 8;
        const float* src = W2 + n * HH + k;
        if (which == 0) {
            ushort* dst = wsw + tt * 8;
            #pragma unroll
            for (int j = 0; j < 8; ++j) dst[j] = f2bf(src[j]);
        } else {
            float w30n = W3[n], w31n = W3[HH + n];
            ushort* dst = wss + tt * 8;
            #pragma unroll
            for (int j = 0; j < 8; ++j) {
                int kk = k + j;
                float fold = w30n * W1[kk * DIN + 0] + w31n * W1[kk * DIN + 1];
                dst[j] = f2bf(src[j] * fold);
            }
        }
    }
}

// r12 = r10 barrier-free wave-complete structure (proven no-spill envelope:
// launch_bounds(512,2), 2 waves/SIMD, 256 regs/wave) + r11's verified 2-GEMM merge,
// with the two weight streams split across different pipes:
//   - W2  fragments from LDS   (128 reads/wave-step, unchanged from r10)
//   - W2s fragments from GLOBAL (L2-resident 128KB; VMEM pipe, no LDS contention)
// Effects vs r10: MFMA 384->256/wave-step, A-build 3 streams->2, frags 96->64,
// acc 24->16.  Pipe-sum: LDS ~51us + MFMA ~37us + VALU ~35us + VMEM(overlapped).
__global__ __launch_bounds__(512, 2) void cnf_kernel(
        const float* __restrict__ xin, const float* __restrict__ W1,
        const float* __restrict__ b2, const float* __restrict__ W3,
        const float* __restrict__ b3, const float* __restrict__ osc,
        const float* __restrict__ a1, const float* __restrict__ rsv,
        const ushort* __restrict__ wsw, const ushort* __restrict__ wss,
        float* __restrict__ out)
{
    extern __shared__ __align__(16) char sm[];

    const int tid = threadIdx.x;
    const int lane = tid & 63;
    const int w = tid >> 6;                      // 8 independent waves
    const int r15 = lane & 15;
    const int q = lane >> 4;
    const int blk = blockIdx.x;
    const int b = blk >> 4;                      // 16 blocks per batch (128 pts/block)

    // ---- stage W2 fragments: linear 131072B copy ----
    {
        uintx4* dst = (uintx4*)sm;
        const uintx4* src = (const uintx4*)wsw;
        #pragma unroll
        for (int i = 0; i < 16; ++i) dst[tid + i * 512] = src[tid + i * 512];
    }
    // ---- stage per-step layer-1 records + W3 projection table ----
    if (tid < HH) {
        const int h = tid;
        const int kt = h >> 5, rem = h & 31, qq = rem >> 3, u = rem & 7;
        const float wa = W1[h * DIN + 0];
        const float wc = W1[h * DIN + 1];
        const float wt = W1[h * DIN + 2];
        const float ra = rsv[h];
        const float ba = a1[b * HH + h];
        #pragma unroll
        for (int s = 0; s < STEPS; ++s) {
            float* rec = (float*)(sm + OFF_W1TAB + s * 4608 + kt * 576 + qq * 144 + u * 16);
            rec[0] = wa; rec[1] = wc; rec[2] = ra; rec[3] = ba + wt * ((float)s * DT);
        }
        float* w3r = (float*)(sm + OFF_W3 + h * 16);
        w3r[0] = W3[h]; w3r[1] = W3[HH + h]; w3r[2] = b2[h]; w3r[3] = 0.f;
    }

    // ---- per-lane state: point (lane&15), replicated across the 4 quads ----
    const int gp = blk * 128 + w * 16 + r15;
    float x0 = xin[gp * 2 + 0];
    float x1 = xin[gp * 2 + 1];
    float cc = 0.f;
    const float osdt = osc[0] * DT;
    const float b30 = b3[0], b31 = b3[1];

    __syncthreads();                             // the ONLY barrier

    const char* wtab = sm + OFF_W1TAB + q * 144;         // this quad's unit records
    const char* wlo  = sm + (size_t)lane * 16;           // W2 frags (LDS), nt 0..7
    const char* whi  = sm + 65536 + (size_t)lane * 16;   // W2 frags (LDS), nt 8..15
    const ushort* ps = wss + (size_t)lane * 8;           // W2s frags (global/L2)

    for (int s = 0; s < STEPS; ++s) {
        // ---- B-frag build: h1 and g1 only (scale folds live in W2s), 8 kt ----
        short8 B0[8], B1[8];
        const char* stab = wtab + s * 4608;
        #pragma unroll
        for (int kt = 0; kt < 8; ++kt) {
            const char* kr = stab + kt * 576;
            uint p0[4], p1[4];
            #pragma unroll
            for (int up = 0; up < 4; ++up) {
                const float4 cA = *(const float4*)(kr + up * 32);
                const float4 cB = *(const float4*)(kr + up * 32 + 16);
                float pa = cA.w + cA.x * x0 + cA.y * x1 + cA.z * cc;
                float pb = cB.w + cB.x * x0 + cB.y * x1 + cB.z * cc;
                float ha = tanh_fast(pa), hb = tanh_fast(pb);
                p0[up] = cvt_pk_bf16(ha, hb);
                p1[up] = cvt_pk_bf16(1.f - ha * ha, 1.f - hb * hb);
            }
            B0[kt] = __builtin_bit_cast(short8, (uintx4){p0[0], p0[1], p0[2], p0[3]});
            B1[kt] = __builtin_bit_cast(short8, (uintx4){p1[0], p1[1], p1[2], p1[3]});
        }

        // ---- 2 GEMMs: R0 = h1.W2^T (W2 from LDS), R12 = g1.W2s^T (W2s from L2) ----
        float sv0 = 0.f, sv1 = 0.f, sdv = 0.f;   // per-lane (= per-point) partials
        #pragma unroll
        for (int pass = 0; pass < 8; ++pass) {
            floatx4 a0[2], a12[2];
            #pragma unroll
            for (int n2 = 0; n2 < 2; ++n2) {
                a0[n2]  = (floatx4){0.f, 0.f, 0.f, 0.f};
                a12[n2] = (floatx4){0.f, 0.f, 0.f, 0.f};
            }
            #pragma unroll
            for (int kt = 0; kt < 8; ++kt) {
                #pragma unroll
                for (int n2 = 0; n2 < 2; ++n2) {
                    const int nt = pass * 2 + n2;
                    const char* bp = (nt < 8 ? wlo : whi) + (size_t)(((nt & 7) * 8 + kt) * 1024);
                    short8 wf  = *(const short8*)bp;                       // LDS
                    short8 wfs = *(const short8*)(ps + (size_t)((nt * 8 + kt) * 512)); // L2
                    a0[n2]  = __builtin_amdgcn_mfma_f32_16x16x32_bf16(wf,  B0[kt], a0[n2],  0, 0, 0);
                    a12[n2] = __builtin_amdgcn_mfma_f32_16x16x32_bf16(wfs, B1[kt], a12[n2], 0, 0, 0);
                }
            }
            // epilogue: lane's acc reg r is j = nt*16 + q*4 + r of its own point
            #pragma unroll
            for (int n2 = 0; n2 < 2; ++n2) {
                const float4* w3p = (const float4*)(sm + OFF_W3
                                   + (size_t)(((pass * 2 + n2) * 16 + q * 4) * 16));
                #pragma unroll
                for (int r = 0; r < 4; ++r) {
                    const float4 w3c = w3p[r];           // broadcast within quad
                    float h2 = tanh_fast(a0[n2][r] + w3c.z);
                    float g2 = 1.f - h2 * h2;
                    sv0 += h2 * w3c.x;
                    sv1 += h2 * w3c.y;
                    sdv += g2 * a12[n2][r];              // W3/W1 factors folded in W2s
                }
            }
        }

        // ---- cross-quad reduction (4 j-subsets) + state update, all in-wave ----
        sv0 += __shfl_xor(sv0, 16);  sv0 += __shfl_xor(sv0, 32);
        sv1 += __shfl_xor(sv1, 16);  sv1 += __shfl_xor(sv1, 32);
        sdv += __shfl_xor(sdv, 16);  sdv += __shfl_xor(sdv, 32);
        x0 += (sv0 + b30) * osdt;
        x1 += (sv1 + b31) * osdt;
        cc += sdv * osdt;
    }

    if (q == 0) {                                // one quad stores (state replicated)
        out[gp * 2 + 0] = x0;
        out[gp * 2 + 1] = x1;
        out[NPTS * 2 + gp] = cc;                 // log_det
    }
}

extern "C" void kernel_launch(void* const* d_in, const int* in_sizes, int n_in,
                              void* d_out, int out_size, void* d_ws, size_t ws_size,
                              hipStream_t stream) {
    const float* x   = (const float*)d_in[0];
    const float* z   = (const float*)d_in[1];
    const float* W1  = (const float*)d_in[2];
    const float* b1  = (const float*)d_in[3];
    const float* W2  = (const float*)d_in[4];
    const float* b2  = (const float*)d_in[5];
    const float* W3  = (const float*)d_in[6];
    const float* b3  = (const float*)d_in[7];
    const float* osc = (const float*)d_in[8];

    // ws layout: a1 [8192 f] @0 | rs [256 f] @32768 | wsw [65536 bf16] @33792
    //            | wss [65536 bf16] @164864   (~290KB total)
    float* a1  = (float*)d_ws;
    float* rsv = (float*)((char*)d_ws + 32768);
    ushort* wsw = (ushort*)((char*)d_ws + 33792);
    ushort* wss = (ushort*)((char*)d_ws + 164864);

    static bool attr_set = false;
    if (!attr_set) {
        hipFuncSetAttribute((const void*)cnf_kernel,
                            hipFuncAttributeMaxDynamicSharedMemorySize, LDS_TOTAL);
        attr_set = true;
    }

    hipLaunchKernelGGL(prep_kernel, dim3(96), dim3(256), 0, stream,
                       z, W1, b1, W2, W3, a1, rsv, wsw, wss);
    hipLaunchKernelGGL(cnf_kernel, dim3(512), dim3(512), LDS_TOTAL, stream,
                       x, W1, b2, W3, b3, osc, a1, rsv, wsw, wss, (float*)d_out);
}

// Round 13
// 289.602 us; speedup vs baseline: 4.2712x; 1.6835x over previous
//
#include <hip/hip_runtime.h>

#define NPTS 65536          // B*N = 32*2048
#define HH 256
#define DIN 131
#define LAT 128
#define STEPS 5
#define DT 0.2f

typedef unsigned int uint;
typedef unsigned short ushort;
typedef __attribute__((ext_vector_type(8))) short short8;
typedef __attribute__((ext_vector_type(4))) float floatx4;
typedef __attribute__((ext_vector_type(4))) uint uintx4;

// Dynamic LDS layout (158208 B):
//   smWsw   @ 0      : 131072 B  W2 bf16 A-fragments (LDS pipe)
//   smW1tab @ 131072 :  23040 B  [s][kt][qq] 8 unit-records {wa,wc,ra,ba_s} (16B, stride 144B)
//   smW3    @ 154112 :   4096 B  float4[j] = {W3[0][j], W3[1][j], b2[j], 0}
#define OFF_W1TAB 131072
#define OFF_W3    154112
#define LDS_TOTAL 158208

__device__ __forceinline__ float tanh_fast(float x) {
    // tanh(x) = 1 - 2/(exp2(2x*log2e)+1); exact at both saturated ends.
    float e = __builtin_amdgcn_exp2f(x * 2.8853900817779268f);
    return 1.0f - 2.0f * __builtin_amdgcn_rcpf(e + 1.0f);
}

__device__ __forceinline__ ushort f2bf(float f) {
    uint u = __builtin_bit_cast(uint, f);
    u += 0x7fffu + ((u >> 16) & 1u);   // RNE
    return (ushort)(u >> 16);
}

// pack two f32 -> 2x bf16 (RNE) in one instruction; lo -> bits[15:0]
__device__ __forceinline__ uint cvt_pk_bf16(float lo, float hi) {
    uint r;
    asm("v_cvt_pk_bf16_f32 %0, %1, %2" : "=v"(r) : "v"(lo), "v"(hi));
    return r;
}

// ---- prep (r12-identical, correctness-verified):
//  a1[b][h] = b1[h] + sum_l z[b][l]*W1[h][3+l]   (t=0 bias)
//  rs[h]    = sum_l W1[h][3+l]
//  wsw: W2 bf16 fragments:  wsw[((nt*8+kt)*64+lane)*8+j] = W2[n][k+j]
//  wss: MERGED tangent matrix W2s[n][k] = W2[n][k]*(W3[0][n]*W1[k][0]+W3[1][n]*W1[k][1])
//       (div = sum_j g2_j * (g1 . W2s^T)_j), same fragment layout.
//  n = nt*16+(lane&15), k = kt*32+(lane>>4)*8
__global__ void prep_kernel(const float* __restrict__ z, const float* __restrict__ W1,
                            const float* __restrict__ b1, const float* __restrict__ W2,
                            const float* __restrict__ W3,
                            float* __restrict__ a1, float* __restrict__ rsv,
                            ushort* __restrict__ wsw, ushort* __restrict__ wss)
{
    int tid = blockIdx.x * 256 + threadIdx.x;
    if (tid < 8192) {
        int b = tid >> 8, h = tid & 255;
        const float* wrow = W1 + h * DIN;
        const float* zb = z + b * LAT;
        float s = b1[h], r = 0.f;
        for (int l = 0; l < LAT; ++l) { float wv = wrow[3 + l]; s += wv * zb[l]; r += wv; }
        a1[tid] = s;
        if (b == 0) rsv[h] = r;
    } else {
        int t = tid - 8192;                    // 0..16383
        int which = t >> 13;                   // 0: wsw (W2), 1: wss (W2s)
        int tt = t & 8191;
        int lane = tt & 63, kt = (tt >> 6) & 7, nt = tt >> 9;
        int n = nt * 16 + (lane & 15);
        int k = kt * 32 + (lane >> 4) * 8;
        const float* src = W2 + n * HH + k;
        if (which == 0) {
            ushort* dst = wsw + tt * 8;
            #pragma unroll
            for (int j = 0; j < 8; ++j) dst[j] = f2bf(src[j]);
        } else {
            float w30n = W3[n], w31n = W3[HH + n];
            ushort* dst = wss + tt * 8;
            #pragma unroll
            for (int j = 0; j < 8; ++j) {
                int kk = k + j;
                float fold = w30n * W1[kk * DIN + 0] + w31n * W1[kk * DIN + 1];
                dst[j] = f2bf(src[j] * fold);
            }
        }
    }
}

// r13 = r12 (barrier-free wave-complete + 2-GEMM merge, W2 from LDS / W2s from L2)
// with ONE change: the pass loop is ROLLED (#pragma unroll 1).  r12's full unroll
// let the scheduler hoist all 128 global W2s loads -> 343MB scratch spill.  A rolled
// loop caps in-flight global loads at one pass (16 loads, 64 regs); per-pass exposed
// L2 latency ~50cyc is covered by 2-wave TLP.  Envelope: launch_bounds(512,2),
// arch <= 128 (proven), frags 64 + acc 16 AGPR-eligible.
__global__ __launch_bounds__(512, 2) void cnf_kernel(
        const float* __restrict__ xin, const float* __restrict__ W1,
        const float* __restrict__ b2, const float* __restrict__ W3,
        const float* __restrict__ b3, const float* __restrict__ osc,
        const float* __restrict__ a1, const float* __restrict__ rsv,
        const ushort* __restrict__ wsw, const ushort* __restrict__ wss,
        float* __restrict__ out)
{
    extern __shared__ __align__(16) char sm[];

    const int tid = threadIdx.x;
    const int lane = tid & 63;
    const int w = tid >> 6;                      // 8 independent waves
    const int r15 = lane & 15;
    const int q = lane >> 4;
    const int blk = blockIdx.x;
    const int b = blk >> 4;                      // 16 blocks per batch (128 pts/block)

    // ---- stage W2 fragments: linear 131072B copy ----
    {
        uintx4* dst = (uintx4*)sm;
        const uintx4* src = (const uintx4*)wsw;
        #pragma unroll
        for (int i = 0; i < 16; ++i) dst[tid + i * 512] = src[tid + i * 512];
    }
    // ---- stage per-step layer-1 records + W3 projection table ----
    if (tid < HH) {
        const int h = tid;
        const int kt = h >> 5, rem = h & 31, qq = rem >> 3, u = rem & 7;
        const float wa = W1[h * DIN + 0];
        const float wc = W1[h * DIN + 1];
        const float wt = W1[h * DIN + 2];
        const float ra = rsv[h];
        const float ba = a1[b * HH + h];
        #pragma unroll
        for (int s = 0; s < STEPS; ++s) {
            float* rec = (float*)(sm + OFF_W1TAB + s * 4608 + kt * 576 + qq * 144 + u * 16);
            rec[0] = wa; rec[1] = wc; rec[2] = ra; rec[3] = ba + wt * ((float)s * DT);
        }
        float* w3r = (float*)(sm + OFF_W3 + h * 16);
        w3r[0] = W3[h]; w3r[1] = W3[HH + h]; w3r[2] = b2[h]; w3r[3] = 0.f;
    }

    // ---- per-lane state: point (lane&15), replicated across the 4 quads ----
    const int gp = blk * 128 + w * 16 + r15;
    float x0 = xin[gp * 2 + 0];
    float x1 = xin[gp * 2 + 1];
    float cc = 0.f;
    const float osdt = osc[0] * DT;
    const float b30 = b3[0], b31 = b3[1];

    __syncthreads();                             // the ONLY barrier

    const char* wtab = sm + OFF_W1TAB + q * 144;         // this quad's unit records
    const char* wlds = sm + (size_t)lane * 16;           // W2 frags (LDS)
    const ushort* ps = wss + (size_t)lane * 8;           // W2s frags (global/L2)

    for (int s = 0; s < STEPS; ++s) {
        // ---- B-frag build: h1 and g1 only (scale folds live in W2s), 8 kt ----
        short8 B0[8], B1[8];
        const char* stab = wtab + s * 4608;
        #pragma unroll
        for (int kt = 0; kt < 8; ++kt) {
            const char* kr = stab + kt * 576;
            uint p0[4], p1[4];
            #pragma unroll
            for (int up = 0; up < 4; ++up) {
                const float4 cA = *(const float4*)(kr + up * 32);
                const float4 cB = *(const float4*)(kr + up * 32 + 16);
                float pa = cA.w + cA.x * x0 + cA.y * x1 + cA.z * cc;
                float pb = cB.w + cB.x * x0 + cB.y * x1 + cB.z * cc;
                float ha = tanh_fast(pa), hb = tanh_fast(pb);
                p0[up] = cvt_pk_bf16(ha, hb);
                p1[up] = cvt_pk_bf16(1.f - ha * ha, 1.f - hb * hb);
            }
            B0[kt] = __builtin_bit_cast(short8, (uintx4){p0[0], p0[1], p0[2], p0[3]});
            B1[kt] = __builtin_bit_cast(short8, (uintx4){p1[0], p1[1], p1[2], p1[3]});
        }

        // ---- 2 GEMMs: R0 = h1.W2^T (LDS), R12 = g1.W2s^T (L2) ----
        // ROLLED pass loop: caps in-flight global loads at 16 (one pass).
        float sv0 = 0.f, sv1 = 0.f, sdv = 0.f;   // per-lane (= per-point) partials
        #pragma unroll 1
        for (int pass = 0; pass < 8; ++pass) {
            floatx4 a0[2], a12[2];
            #pragma unroll
            for (int n2 = 0; n2 < 2; ++n2) {
                a0[n2]  = (floatx4){0.f, 0.f, 0.f, 0.f};
                a12[n2] = (floatx4){0.f, 0.f, 0.f, 0.f};
            }
            const char* blp = wlds + (size_t)pass * 16384;       // LDS base this pass
            const ushort* bgp = ps + (size_t)pass * 8192;        // global base this pass
            #pragma unroll
            for (int kt = 0; kt < 8; ++kt) {
                #pragma unroll
                for (int n2 = 0; n2 < 2; ++n2) {
                    short8 wf  = *(const short8*)(blp + (size_t)((n2 * 8 + kt) * 1024));
                    short8 wfs = *(const short8*)(bgp + (size_t)((n2 * 8 + kt) * 512));
                    a0[n2]  = __builtin_amdgcn_mfma_f32_16x16x32_bf16(wf,  B0[kt], a0[n2],  0, 0, 0);
                    a12[n2] = __builtin_amdgcn_mfma_f32_16x16x32_bf16(wfs, B1[kt], a12[n2], 0, 0, 0);
                }
            }
            // epilogue: lane's acc reg r is j = nt*16 + q*4 + r of its own point
            #pragma unroll
            for (int n2 = 0; n2 < 2; ++n2) {
                const float4* w3p = (const float4*)(sm + OFF_W3
                                   + (size_t)(((pass * 2 + n2) * 16 + q * 4) * 16));
                #pragma unroll
                for (int r = 0; r < 4; ++r) {
                    const float4 w3c = w3p[r];           // broadcast within quad
                    float h2 = tanh_fast(a0[n2][r] + w3c.z);
                    float g2 = 1.f - h2 * h2;
                    sv0 += h2 * w3c.x;
                    sv1 += h2 * w3c.y;
                    sdv += g2 * a12[n2][r];              // W3/W1 factors folded in W2s
                }
            }
        }

        // ---- cross-quad reduction (4 j-subsets) + state update, all in-wave ----
        sv0 += __shfl_xor(sv0, 16);  sv0 += __shfl_xor(sv0, 32);
        sv1 += __shfl_xor(sv1, 16);  sv1 += __shfl_xor(sv1, 32);
        sdv += __shfl_xor(sdv, 16);  sdv += __shfl_xor(sdv, 32);
        x0 += (sv0 + b30) * osdt;
        x1 += (sv1 + b31) * osdt;
        cc += sdv * osdt;
    }

    if (q == 0) {                                // one quad stores (state replicated)
        out[gp * 2 + 0] = x0;
        out[gp * 2 + 1] = x1;
        out[NPTS * 2 + gp] = cc;                 // log_det
    }
}

extern "C" void kernel_launch(void* const* d_in, const int* in_sizes, int n_in,
                              void* d_out, int out_size, void* d_ws, size_t ws_size,
                              hipStream_t stream) {
    const float* x   = (const float*)d_in[0];
    const float* z   = (const float*)d_in[1];
    const float* W1  = (const float*)d_in[2];
    const float* b1  = (const float*)d_in[3];
    const float* W2  = (const float*)d_in[4];
    const float* b2  = (const float*)d_in[5];
    const float* W3  = (const float*)d_in[6];
    const float* b3  = (const float*)d_in[7];
    const float* osc = (const float*)d_in[8];

    // ws layout: a1 [8192 f] @0 | rs [256 f] @32768 | wsw [65536 bf16] @33792
    //            | wss [65536 bf16] @164864   (~290KB total)
    float* a1  = (float*)d_ws;
    float* rsv = (float*)((char*)d_ws + 32768);
    ushort* wsw = (ushort*)((char*)d_ws + 33792);
    ushort* wss = (ushort*)((char*)d_ws + 164864);

    static bool attr_set = false;
    if (!attr_set) {
        hipFuncSetAttribute((const void*)cnf_kernel,
                            hipFuncAttributeMaxDynamicSharedMemorySize, LDS_TOTAL);
        attr_set = true;
    }

    hipLaunchKernelGGL(prep_kernel, dim3(96), dim3(256), 0, stream,
                       z, W1, b1, W2, W3, a1, rsv, wsw, wss);
    hipLaunchKernelGGL(cnf_kernel, dim3(512), dim3(512), LDS_TOTAL, stream,
                       x, W1, b2, W3, b3, osc, a1, rsv, wsw, wss, (float*)d_out);
}

// Round 14
// 274.476 us; speedup vs baseline: 4.5066x; 1.0551x over previous
//
#include <hip/hip_runtime.h>

#define NPTS 65536          // B*N = 32*2048
#define HH 256
#define DIN 131
#define LAT 128
#define STEPS 5
#define DT 0.2f

typedef unsigned int uint;
typedef unsigned short ushort;
typedef __attribute__((ext_vector_type(8))) short short8;
typedef __attribute__((ext_vector_type(4))) float floatx4;
typedef __attribute__((ext_vector_type(4))) uint uintx4;

// Dynamic LDS layout (158208 B):
//   smWsw   @ 0      : 131072 B  W2 bf16 A-fragments (LDS pipe)
//   smW1tab @ 131072 :  23040 B  [s][kt][qq] 8 unit-records {wa,wc,ra,ba_s} (16B, stride 144B)
//   smW3    @ 154112 :   4096 B  float4[j] = {W3[0][j], W3[1][j], b2[j], 0}
#define OFF_W1TAB 131072
#define OFF_W3    154112
#define LDS_TOTAL 158208

__device__ __forceinline__ float tanh_fast(float x) {
    // tanh(x) = 1 - 2/(exp2(2x*log2e)+1); exact at both saturated ends.
    float e = __builtin_amdgcn_exp2f(x * 2.8853900817779268f);
    return 1.0f - 2.0f * __builtin_amdgcn_rcpf(e + 1.0f);
}

__device__ __forceinline__ ushort f2bf(float f) {
    uint u = __builtin_bit_cast(uint, f);
    u += 0x7fffu + ((u >> 16) & 1u);   // RNE
    return (ushort)(u >> 16);
}

// pack two f32 -> 2x bf16 (RNE) in one instruction; lo -> bits[15:0]
__device__ __forceinline__ uint cvt_pk_bf16(float lo, float hi) {
    uint r;
    asm("v_cvt_pk_bf16_f32 %0, %1, %2" : "=v"(r) : "v"(lo), "v"(hi));
    return r;
}

// ---- prep (r12/r13-identical, correctness-verified):
//  a1[b][h] = b1[h] + sum_l z[b][l]*W1[h][3+l]   (t=0 bias)
//  rs[h]    = sum_l W1[h][3+l]
//  wsw: W2 bf16 fragments:  wsw[((nt*8+kt)*64+lane)*8+j] = W2[n][k+j]
//  wss: MERGED tangent matrix W2s[n][k] = W2[n][k]*(W3[0][n]*W1[k][0]+W3[1][n]*W1[k][1])
//       (div = sum_j g2_j * (g1 . W2s^T)_j), same fragment layout.
//  n = nt*16+(lane&15), k = kt*32+(lane>>4)*8
__global__ void prep_kernel(const float* __restrict__ z, const float* __restrict__ W1,
                            const float* __restrict__ b1, const float* __restrict__ W2,
                            const float* __restrict__ W3,
                            float* __restrict__ a1, float* __restrict__ rsv,
                            ushort* __restrict__ wsw, ushort* __restrict__ wss)
{
    int tid = blockIdx.x * 256 + threadIdx.x;
    if (tid < 8192) {
        int b = tid >> 8, h = tid & 255;
        const float* wrow = W1 + h * DIN;
        const float* zb = z + b * LAT;
        float s = b1[h], r = 0.f;
        for (int l = 0; l < LAT; ++l) { float wv = wrow[3 + l]; s += wv * zb[l]; r += wv; }
        a1[tid] = s;
        if (b == 0) rsv[h] = r;
    } else {
        int t = tid - 8192;                    // 0..16383
        int which = t >> 13;                   // 0: wsw (W2), 1: wss (W2s)
        int tt = t & 8191;
        int lane = tt & 63, kt = (tt >> 6) & 7, nt = tt >> 9;
        int n = nt * 16 + (lane & 15);
        int k = kt * 32 + (lane >> 4) * 8;
        const float* src = W2 + n * HH + k;
        if (which == 0) {
            ushort* dst = wsw + tt * 8;
            #pragma unroll
            for (int j = 0; j < 8; ++j) dst[j] = f2bf(src[j]);
        } else {
            float w30n = W3[n], w31n = W3[HH + n];
            ushort* dst = wss + tt * 8;
            #pragma unroll
            for (int j = 0; j < 8; ++j) {
                int kk = k + j;
                float fold = w30n * W1[kk * DIN + 0] + w31n * W1[kk * DIN + 1];
                dst[j] = f2bf(src[j] * fold);
            }
        }
    }
}

// r14 = r13 (barrier-free wave-complete + 2-GEMM merge, W2 from LDS / W2s from L2,
// rolled pass loop) + MANUAL HALF-PASS DOUBLE-BUFFER PREFETCH of the W2s stream:
//   c0/c1 = two named 8x short8 buffers (32 VGPR each).  Per pass: issue c1=(p,h1),
//   consume c0 (kt0-3, 16 MFMA ~310cyc covers L2 ~250cyc), issue c0=(p+1,h0),
//   consume c1 (kt4-7), epilogue.  In a ROLLED loop the WAR hazard on the named
//   buffers structurally caps in-flight loads at one half-chunk -- r12's hoist-spill
//   and r13's zero-lookahead stall are both excluded by construction.
// Budget: r13 measured 60 arch + 64 buffers = ~124 <= 128 (frags/acc in AGPRs).
__global__ __launch_bounds__(512, 2) void cnf_kernel(
        const float* __restrict__ xin, const float* __restrict__ W1,
        const float* __restrict__ b2, const float* __restrict__ W3,
        const float* __restrict__ b3, const float* __restrict__ osc,
        const float* __restrict__ a1, const float* __restrict__ rsv,
        const ushort* __restrict__ wsw, const ushort* __restrict__ wss,
        float* __restrict__ out)
{
    extern __shared__ __align__(16) char sm[];

    const int tid = threadIdx.x;
    const int lane = tid & 63;
    const int w = tid >> 6;                      // 8 independent waves
    const int r15 = lane & 15;
    const int q = lane >> 4;
    const int blk = blockIdx.x;
    const int b = blk >> 4;                      // 16 blocks per batch (128 pts/block)

    // ---- stage W2 fragments: linear 131072B copy ----
    {
        uintx4* dst = (uintx4*)sm;
        const uintx4* src = (const uintx4*)wsw;
        #pragma unroll
        for (int i = 0; i < 16; ++i) dst[tid + i * 512] = src[tid + i * 512];
    }
    // ---- stage per-step layer-1 records + W3 projection table ----
    if (tid < HH) {
        const int h = tid;
        const int kt = h >> 5, rem = h & 31, qq = rem >> 3, u = rem & 7;
        const float wa = W1[h * DIN + 0];
        const float wc = W1[h * DIN + 1];
        const float wt = W1[h * DIN + 2];
        const float ra = rsv[h];
        const float ba = a1[b * HH + h];
        #pragma unroll
        for (int s = 0; s < STEPS; ++s) {
            float* rec = (float*)(sm + OFF_W1TAB + s * 4608 + kt * 576 + qq * 144 + u * 16);
            rec[0] = wa; rec[1] = wc; rec[2] = ra; rec[3] = ba + wt * ((float)s * DT);
        }
        float* w3r = (float*)(sm + OFF_W3 + h * 16);
        w3r[0] = W3[h]; w3r[1] = W3[HH + h]; w3r[2] = b2[h]; w3r[3] = 0.f;
    }

    // ---- per-lane state: point (lane&15), replicated across the 4 quads ----
    const int gp = blk * 128 + w * 16 + r15;
    float x0 = xin[gp * 2 + 0];
    float x1 = xin[gp * 2 + 1];
    float cc = 0.f;
    const float osdt = osc[0] * DT;
    const float b30 = b3[0], b31 = b3[1];

    __syncthreads();                             // the ONLY barrier

    const char* wtab = sm + OFF_W1TAB + q * 144;         // this quad's unit records
    const char* wlds = sm + (size_t)lane * 16;           // W2 frags (LDS)
    const ushort* ps = wss + (size_t)lane * 8;           // W2s frags (global/L2)

    for (int s = 0; s < STEPS; ++s) {
        // ---- prefetch (pass0, half0) of W2s; hides under the B-frag build ----
        short8 c0[8], c1[8];
        #pragma unroll
        for (int i = 0; i < 8; ++i)
            c0[i] = *(const short8*)(ps + (size_t)((i >> 2) * 4096 + (i & 3) * 512));

        // ---- B-frag build: h1 and g1 only (scale folds live in W2s), 8 kt ----
        short8 B0[8], B1[8];
        const char* stab = wtab + s * 4608;
        #pragma unroll
        for (int kt = 0; kt < 8; ++kt) {
            const char* kr = stab + kt * 576;
            uint p0[4], p1[4];
            #pragma unroll
            for (int up = 0; up < 4; ++up) {
                const float4 cA = *(const float4*)(kr + up * 32);
                const float4 cB = *(const float4*)(kr + up * 32 + 16);
                float pa = cA.w + cA.x * x0 + cA.y * x1 + cA.z * cc;
                float pb = cB.w + cB.x * x0 + cB.y * x1 + cB.z * cc;
                float ha = tanh_fast(pa), hb = tanh_fast(pb);
                p0[up] = cvt_pk_bf16(ha, hb);
                p1[up] = cvt_pk_bf16(1.f - ha * ha, 1.f - hb * hb);
            }
            B0[kt] = __builtin_bit_cast(short8, (uintx4){p0[0], p0[1], p0[2], p0[3]});
            B1[kt] = __builtin_bit_cast(short8, (uintx4){p1[0], p1[1], p1[2], p1[3]});
        }

        // ---- 2 GEMMs: R0 = h1.W2^T (LDS), R12 = g1.W2s^T (L2, prefetched) ----
        float sv0 = 0.f, sv1 = 0.f, sdv = 0.f;   // per-lane (= per-point) partials
        #pragma unroll 1
        for (int pass = 0; pass < 8; ++pass) {
            const ushort* bg  = ps + (size_t)pass * 8192;
            const ushort* bgn = ps + (size_t)(pass < 7 ? pass + 1 : 7) * 8192;
            const char*  blp  = wlds + (size_t)pass * 16384;

            floatx4 a0[2], a12[2];
            a0[0]  = (floatx4){0.f, 0.f, 0.f, 0.f};
            a0[1]  = (floatx4){0.f, 0.f, 0.f, 0.f};
            a12[0] = (floatx4){0.f, 0.f, 0.f, 0.f};
            a12[1] = (floatx4){0.f, 0.f, 0.f, 0.f};

            // issue c1 = (pass, half1): kt 4..7, both n2
            #pragma unroll
            for (int i = 0; i < 8; ++i)
                c1[i] = *(const short8*)(bg + (size_t)((i >> 2) * 4096 + (4 + (i & 3)) * 512));

            // consume c0: kt 0..3
            #pragma unroll
            for (int kk = 0; kk < 4; ++kk) {
                short8 wf0 = *(const short8*)(blp + (size_t)((0 * 8 + kk) * 1024));
                short8 wf1 = *(const short8*)(blp + (size_t)((1 * 8 + kk) * 1024));
                a0[0]  = __builtin_amdgcn_mfma_f32_16x16x32_bf16(wf0,      B0[kk], a0[0],  0, 0, 0);
                a12[0] = __builtin_amdgcn_mfma_f32_16x16x32_bf16(c0[kk],   B1[kk], a12[0], 0, 0, 0);
                a0[1]  = __builtin_amdgcn_mfma_f32_16x16x32_bf16(wf1,      B0[kk], a0[1],  0, 0, 0);
                a12[1] = __builtin_amdgcn_mfma_f32_16x16x32_bf16(c0[4+kk], B1[kk], a12[1], 0, 0, 0);
            }

            // issue c0 = (pass+1, half0): kt 0..3, both n2 (p=7: benign re-read)
            #pragma unroll
            for (int i = 0; i < 8; ++i)
                c0[i] = *(const short8*)(bgn + (size_t)((i >> 2) * 4096 + (i & 3) * 512));

            // consume c1: kt 4..7
            #pragma unroll
            for (int kk = 0; kk < 4; ++kk) {
                const int kt = 4 + kk;
                short8 wf0 = *(const short8*)(blp + (size_t)((0 * 8 + kt) * 1024));
                short8 wf1 = *(const short8*)(blp + (size_t)((1 * 8 + kt) * 1024));
                a0[0]  = __builtin_amdgcn_mfma_f32_16x16x32_bf16(wf0,      B0[kt], a0[0],  0, 0, 0);
                a12[0] = __builtin_amdgcn_mfma_f32_16x16x32_bf16(c1[kk],   B1[kt], a12[0], 0, 0, 0);
                a0[1]  = __builtin_amdgcn_mfma_f32_16x16x32_bf16(wf1,      B0[kt], a0[1],  0, 0, 0);
                a12[1] = __builtin_amdgcn_mfma_f32_16x16x32_bf16(c1[4+kk], B1[kt], a12[1], 0, 0, 0);
            }

            // epilogue: lane's acc reg r is j = nt*16 + q*4 + r of its own point
            #pragma unroll
            for (int n2 = 0; n2 < 2; ++n2) {
                const float4* w3p = (const float4*)(sm + OFF_W3
                                   + (size_t)(((pass * 2 + n2) * 16 + q * 4) * 16));
                #pragma unroll
                for (int r = 0; r < 4; ++r) {
                    const float4 w3c = w3p[r];           // broadcast within quad
                    float h2 = tanh_fast(a0[n2][r] + w3c.z);
                    float g2 = 1.f - h2 * h2;
                    sv0 += h2 * w3c.x;
                    sv1 += h2 * w3c.y;
                    sdv += g2 * a12[n2][r];              // W3/W1 factors folded in W2s
                }
            }
        }

        // ---- cross-quad reduction (4 j-subsets) + state update, all in-wave ----
        sv0 += __shfl_xor(sv0, 16);  sv0 += __shfl_xor(sv0, 32);
        sv1 += __shfl_xor(sv1, 16);  sv1 += __shfl_xor(sv1, 32);
        sdv += __shfl_xor(sdv, 16);  sdv += __shfl_xor(sdv, 32);
        x0 += (sv0 + b30) * osdt;
        x1 += (sv1 + b31) * osdt;
        cc += sdv * osdt;
    }

    if (q == 0) {                                // one quad stores (state replicated)
        out[gp * 2 + 0] = x0;
        out[gp * 2 + 1] = x1;
        out[NPTS * 2 + gp] = cc;                 // log_det
    }
}

extern "C" void kernel_launch(void* const* d_in, const int* in_sizes, int n_in,
                              void* d_out, int out_size, void* d_ws, size_t ws_size,
                              hipStream_t stream) {
    const float* x   = (const float*)d_in[0];
    const float* z   = (const float*)d_in[1];
    const float* W1  = (const float*)d_in[2];
    const float* b1  = (const float*)d_in[3];
    const float* W2  = (const float*)d_in[4];
    const float* b2  = (const float*)d_in[5];
    const float* W3  = (const float*)d_in[6];
    const float* b3  = (const float*)d_in[7];
    const float* osc = (const float*)d_in[8];

    // ws layout: a1 [8192 f] @0 | rs [256 f] @32768 | wsw [65536 bf16] @33792
    //            | wss [65536 bf16] @164864   (~290KB total)
    float* a1  = (float*)d_ws;
    float* rsv = (float*)((char*)d_ws + 32768);
    ushort* wsw = (ushort*)((char*)d_ws + 33792);
    ushort* wss = (ushort*)((char*)d_ws + 164864);

    static bool attr_set = false;
    if (!attr_set) {
        hipFuncSetAttribute((const void*)cnf_kernel,
                            hipFuncAttributeMaxDynamicSharedMemorySize, LDS_TOTAL);
        attr_set = true;
    }

    hipLaunchKernelGGL(prep_kernel, dim3(96), dim3(256), 0, stream,
                       z, W1, b1, W2, W3, a1, rsv, wsw, wss);
    hipLaunchKernelGGL(cnf_kernel, dim3(512), dim3(512), LDS_TOTAL, stream,
                       x, W1, b2, W3, b3, osc, a1, rsv, wsw, wss, (float*)d_out);
}

// Round 15
// 206.161 us; speedup vs baseline: 6.0000x; 1.3314x over previous
//
#include <hip/hip_runtime.h>

#define NPTS 65536          // B*N = 32*2048
#define HH 256
#define DIN 131
#define LAT 128
#define STEPS 5
#define DT 0.2f

typedef unsigned int uint;
typedef unsigned short ushort;
typedef __attribute__((ext_vector_type(8))) short short8;
typedef __attribute__((ext_vector_type(4))) float floatx4;
typedef __attribute__((ext_vector_type(4))) uint uintx4;

// Dynamic LDS layout (158208 B total):
//   smWsw   @ 0      : 131072 B  W2 bf16 fragments (MFMA A operand;
//                                wsw layout is already A-frag: row j = lane&15, k-slice = lane>>4)
//   smW1tab @ 131072 :  23040 B  [s][kt][q] groups of 8 unit-records {wa,wc,ra,ba_s} (16B),
//                                group stride 144B (pad -> the 4 quads hit distinct banks)
//   smW3    @ 154112 :   4096 B  float4[j] = {W3[0][j], W3[1][j], b2[j], 0}
#define OFF_W1TAB 131072
#define OFF_W3    154112
#define LDS_TOTAL 158208

__device__ __forceinline__ float tanh_fast(float x) {
    // tanh(x) = 1 - 2/(exp2(2x*log2e)+1); exact at both saturated ends.
    float e = __builtin_amdgcn_exp2f(x * 2.8853900817779268f);
    return 1.0f - 2.0f * __builtin_amdgcn_rcpf(e + 1.0f);
}

__device__ __forceinline__ ushort f2bf(float f) {
    uint u = __builtin_bit_cast(uint, f);
    u += 0x7fffu + ((u >> 16) & 1u);   // RNE
    return (ushort)(u >> 16);
}

// pack two f32 -> 2x bf16 (RNE) in one instruction; lo -> bits[15:0]
__device__ __forceinline__ uint cvt_pk_bf16(float lo, float hi) {
    uint r;
    asm("v_cvt_pk_bf16_f32 %0, %1, %2" : "=v"(r) : "v"(lo), "v"(hi));
    return r;
}

// ---- prep (r10-identical, correctness-verified):
//  a1[b][h] = b1[h] + sum_l z[b][l]*W1[h][3+l]   (t=0 bias)
//  rs[h] = sum_l W1[h][3+l]
//  wsw[((nt*8+kt)*64+lane)*8+j] = W2[nt*16+(lane&15)][kt*32+(lane>>4)*8+j]
__global__ void prep_kernel(const float* __restrict__ z, const float* __restrict__ W1,
                            const float* __restrict__ b1, const float* __restrict__ W2,
                            float* __restrict__ a1, float* __restrict__ rsv,
                            ushort* __restrict__ wsw)
{
    int tid = blockIdx.x * 256 + threadIdx.x;
    if (tid < 8192) {
        int b = tid >> 8, h = tid & 255;
        const float* wrow = W1 + h * DIN;
        const float* zb = z + b * LAT;
        float s = b1[h], r = 0.f;
        for (int l = 0; l < LAT; ++l) { float wv = wrow[3 + l]; s += wv * zb[l]; r += wv; }
        a1[tid] = s;
        if (b == 0) rsv[h] = r;
    } else {
        int t = tid - 8192;                    // 0..8191
        int lane = t & 63, kt = (t >> 6) & 7, nt = t >> 9;
        int n = nt * 16 + (lane & 15);
        int k = kt * 32 + (lane >> 4) * 8;
        const float* src = W2 + n * HH + k;
        ushort* dst = wsw + t * 8;
        #pragma unroll
        for (int j = 0; j < 8; ++j) dst[j] = f2bf(src[j]);
    }
}

// r15 = r10 VERBATIM (the session's verified best: 180us cnf / 212.5us total;
// barrier-free wave-complete, all-LDS weights, VGPR 100, zero spill/conflicts)
// + s_setprio(1) around each pass's MFMA cluster.  r10's waves free-run with
// no barriers -> 16 waves/CU at DIFFERENT phases (build-VALU vs GEMM-MFMA):
// the role-diverse regime where setprio measured +4-7% (vs null in
// barrier-locked kernels).  The global-W2s merge lane (r11-r14) is closed:
// the compiler either hoists (spill) or sinks (stall) the stream; 2-GEMM
// merge requires 256KB of weights which does not fit 160KB LDS.
__global__ __launch_bounds__(512, 2) void cnf_kernel(
        const float* __restrict__ xin, const float* __restrict__ W1,
        const float* __restrict__ b2, const float* __restrict__ W3,
        const float* __restrict__ b3, const float* __restrict__ osc,
        const float* __restrict__ a1, const float* __restrict__ rsv,
        const ushort* __restrict__ wsw, float* __restrict__ out)
{
    extern __shared__ __align__(16) char sm[];

    const int tid = threadIdx.x;
    const int lane = tid & 63;
    const int w = tid >> 6;                      // 8 independent waves
    const int r15 = lane & 15;
    const int q = lane >> 4;
    const int blk = blockIdx.x;
    const int b = blk >> 4;                      // 16 blocks per batch (128 pts/block)

    // ---- stage W2 fragments: linear 131072B copy ----
    {
        uintx4* dst = (uintx4*)sm;
        const uintx4* src = (const uintx4*)wsw;
        #pragma unroll
        for (int i = 0; i < 16; ++i) dst[tid + i * 512] = src[tid + i * 512];
    }
    // ---- stage per-step layer-1 records + W3 projection table ----
    if (tid < HH) {
        const int h = tid;
        const int kt = h >> 5, rem = h & 31, qq = rem >> 3, u = rem & 7;
        const float wa = W1[h * DIN + 0];
        const float wc = W1[h * DIN + 1];
        const float wt = W1[h * DIN + 2];
        const float ra = rsv[h];
        const float ba = a1[b * HH + h];
        #pragma unroll
        for (int s = 0; s < STEPS; ++s) {
            float* rec = (float*)(sm + OFF_W1TAB + s * 4608 + kt * 576 + qq * 144 + u * 16);
            rec[0] = wa; rec[1] = wc; rec[2] = ra; rec[3] = ba + wt * ((float)s * DT);
        }
        float* w3r = (float*)(sm + OFF_W3 + h * 16);
        w3r[0] = W3[h]; w3r[1] = W3[HH + h]; w3r[2] = b2[h]; w3r[3] = 0.f;
    }

    // ---- per-lane state: point (lane&15), replicated across the 4 quads ----
    const int gp = blk * 128 + w * 16 + r15;
    float x0 = xin[gp * 2 + 0];
    float x1 = xin[gp * 2 + 1];
    float cc = 0.f;
    const float osdt = osc[0] * DT;
    const float b30 = b3[0], b31 = b3[1];

    __syncthreads();                             // the ONLY barrier

    const char* wtab = sm + OFF_W1TAB + q * 144; // this quad's unit records
    const char* wlo  = sm + (size_t)lane * 16;           // W2 frags, nt 0..7
    const char* whi  = sm + 65536 + (size_t)lane * 16;   // W2 frags, nt 8..15

    for (int s = 0; s < STEPS; ++s) {
        // ---- B-frag build (activations): 3 streams x 8 kt ----
        short8 B0[8], B1[8], B2[8];
        const char* stab = wtab + s * 4608;
        #pragma unroll
        for (int kt = 0; kt < 8; ++kt) {
            const char* kr = stab + kt * 576;
            uint p0[4], p1[4], p2[4];
            #pragma unroll
            for (int up = 0; up < 4; ++up) {
                const float4 cA = *(const float4*)(kr + up * 32);
                const float4 cB = *(const float4*)(kr + up * 32 + 16);
                float pa = cA.w + cA.x * x0 + cA.y * x1 + cA.z * cc;
                float pb = cB.w + cB.x * x0 + cB.y * x1 + cB.z * cc;
                float ha = tanh_fast(pa), hb = tanh_fast(pb);
                float ga = 1.f - ha * ha, gb = 1.f - hb * hb;
                p0[up] = cvt_pk_bf16(ha, hb);
                p1[up] = cvt_pk_bf16(ga * cA.x, gb * cB.x);
                p2[up] = cvt_pk_bf16(ga * cA.y, gb * cB.y);
            }
            B0[kt] = __builtin_bit_cast(short8, (uintx4){p0[0], p0[1], p0[2], p0[3]});
            B1[kt] = __builtin_bit_cast(short8, (uintx4){p1[0], p1[1], p1[2], p1[3]});
            B2[kt] = __builtin_bit_cast(short8, (uintx4){p2[0], p2[1], p2[2], p2[3]});
        }

        // ---- GEMM: 8 nt-passes, acc[3][2]=24 regs; W2 A-frags streamed from LDS ----
        float sv0 = 0.f, sv1 = 0.f, sdv = 0.f;    // per-lane (= per-point) partials
        #pragma unroll
        for (int pass = 0; pass < 8; ++pass) {
            floatx4 a0[2], a1v[2], a2[2];
            #pragma unroll
            for (int n2 = 0; n2 < 2; ++n2) {
                a0[n2]  = (floatx4){0.f, 0.f, 0.f, 0.f};
                a1v[n2] = (floatx4){0.f, 0.f, 0.f, 0.f};
                a2[n2]  = (floatx4){0.f, 0.f, 0.f, 0.f};
            }
            __builtin_amdgcn_s_setprio(1);       // free-running waves: favor the MFMA phase
            #pragma unroll
            for (int kt = 0; kt < 8; ++kt) {
                #pragma unroll
                for (int n2 = 0; n2 < 2; ++n2) {
                    const int nt = pass * 2 + n2;
                    const char* bp = (nt < 8 ? wlo : whi) + (size_t)(((nt & 7) * 8 + kt) * 1024);
                    short8 wf = *(const short8*)bp;      // one load feeds all 3 streams
                    a0[n2]  = __builtin_amdgcn_mfma_f32_16x16x32_bf16(wf, B0[kt], a0[n2],  0, 0, 0);
                    a1v[n2] = __builtin_amdgcn_mfma_f32_16x16x32_bf16(wf, B1[kt], a1v[n2], 0, 0, 0);
                    a2[n2]  = __builtin_amdgcn_mfma_f32_16x16x32_bf16(wf, B2[kt], a2[n2],  0, 0, 0);
                }
            }
            __builtin_amdgcn_s_setprio(0);
            // epilogue: lane's acc reg r is j = nt*16 + q*4 + r of its own point
            #pragma unroll
            for (int n2 = 0; n2 < 2; ++n2) {
                const int nt = pass * 2 + n2;
                const float4* w3p = (const float4*)(sm + OFF_W3 + (size_t)(nt * 16 + q * 4) * 16);
                #pragma unroll
                for (int r = 0; r < 4; ++r) {
                    const float4 w3c = w3p[r];           // broadcast within quad
                    float h2 = tanh_fast(a0[n2][r] + w3c.z);
                    float g2 = 1.f - h2 * h2;
                    sv0 += h2 * w3c.x;
                    sv1 += h2 * w3c.y;
                    sdv += g2 * (a1v[n2][r] * w3c.x + a2[n2][r] * w3c.y);
                }
            }
        }

        // ---- cross-quad reduction (4 j-subsets) + state update, all in-wave ----
        sv0 += __shfl_xor(sv0, 16);  sv0 += __shfl_xor(sv0, 32);
        sv1 += __shfl_xor(sv1, 16);  sv1 += __shfl_xor(sv1, 32);
        sdv += __shfl_xor(sdv, 16);  sdv += __shfl_xor(sdv, 32);
        x0 += (sv0 + b30) * osdt;
        x1 += (sv1 + b31) * osdt;
        cc += sdv * osdt;
    }

    if (q == 0) {                                // one quad stores (state replicated)
        out[gp * 2 + 0] = x0;
        out[gp * 2 + 1] = x1;
        out[NPTS * 2 + gp] = cc;                 // log_det
    }
}

extern "C" void kernel_launch(void* const* d_in, const int* in_sizes, int n_in,
                              void* d_out, int out_size, void* d_ws, size_t ws_size,
                              hipStream_t stream) {
    const float* x   = (const float*)d_in[0];
    const float* z   = (const float*)d_in[1];
    const float* W1  = (const float*)d_in[2];
    const float* b1  = (const float*)d_in[3];
    const float* W2  = (const float*)d_in[4];
    const float* b2  = (const float*)d_in[5];
    const float* W3  = (const float*)d_in[6];
    const float* b3  = (const float*)d_in[7];
    const float* osc = (const float*)d_in[8];

    // ws layout: a1 [8192 f] @0 | rs [256 f] @32768B | wsw [65536 bf16] @33792B (~165KB)
    float* a1  = (float*)d_ws;
    float* rsv = (float*)((char*)d_ws + 32768);
    ushort* wsw = (ushort*)((char*)d_ws + 33792);

    static bool attr_set = false;
    if (!attr_set) {
        hipFuncSetAttribute((const void*)cnf_kernel,
                            hipFuncAttributeMaxDynamicSharedMemorySize, LDS_TOTAL);
        attr_set = true;
    }

    hipLaunchKernelGGL(prep_kernel, dim3(64), dim3(256), 0, stream, z, W1, b1, W2, a1, rsv, wsw);
    hipLaunchKernelGGL(cnf_kernel, dim3(512), dim3(512), LDS_TOTAL, stream,
                       x, W1, b2, W3, b3, osc, a1, rsv, wsw, (float*)d_out);
}